// Round 1
// baseline (677.631 us; speedup 1.0000x reference)
//
#include <hip/hip_runtime.h>
#include <math.h>

#define NN 50000
#define EE 800000
#define INCH 128
#define HID 64
#define OUTCH 40
#define NUM_LAYERS 8

__device__ __forceinline__ float frelu(float v) { return v > 0.f ? v : 0.f; }

// ---------------- entry: x0 = relu(x @ W_in + b_in) ----------------
__global__ __launch_bounds__(256) void entry_gemm(
    const float* __restrict__ x, const float* __restrict__ W,
    const float* __restrict__ b, float* __restrict__ x0) {
  __shared__ float Wl[INCH * HID];   // [k][c], 32 KB
  __shared__ float xT[INCH][68];     // [k][r], padded for alignment
  __shared__ float bl[HID];
  const int t = threadIdx.x;
  const int base = blockIdx.x * 64;

  // stage W (8192 floats) via float4
  #pragma unroll
  for (int i = 0; i < 8; ++i) {
    const int f4 = i * 256 + t;
    *(float4*)&Wl[f4 * 4] = *(const float4*)&W[f4 * 4];
  }
  if (t < HID) bl[t] = b[t];
  // stage x tile transposed (64 rows x 128 k)
  #pragma unroll
  for (int i = 0; i < 8; ++i) {
    const int f4 = i * 256 + t;
    const int row = f4 >> 5;          // 32 float4 per row
    const int col = (f4 & 31) * 4;
    float4 v = make_float4(0.f, 0.f, 0.f, 0.f);
    if (base + row < NN) v = *(const float4*)&x[(size_t)(base + row) * INCH + col];
    xT[col + 0][row] = v.x; xT[col + 1][row] = v.y;
    xT[col + 2][row] = v.z; xT[col + 3][row] = v.w;
  }
  __syncthreads();

  const int r0 = (t >> 4) * 4;
  const int c0 = (t & 15) * 4;
  float acc[4][4] = {};
  #pragma unroll 4
  for (int k = 0; k < INCH; ++k) {
    const float4 a = *(const float4*)&xT[k][r0];
    const float4 wv = *(const float4*)&Wl[k * HID + c0];
    const float av[4] = {a.x, a.y, a.z, a.w};
    const float wvv[4] = {wv.x, wv.y, wv.z, wv.w};
    #pragma unroll
    for (int i = 0; i < 4; ++i)
      #pragma unroll
      for (int j = 0; j < 4; ++j) acc[i][j] += av[i] * wvv[j];
  }

  #pragma unroll
  for (int i = 0; i < 4; ++i) {
    const int row = base + r0 + i;
    if (row < NN) {
      float4 o;
      o.x = frelu(acc[i][0] + bl[c0 + 0]);
      o.y = frelu(acc[i][1] + bl[c0 + 1]);
      o.z = frelu(acc[i][2] + bl[c0 + 2]);
      o.w = frelu(acc[i][3] + bl[c0 + 3]);
      *(float4*)&x0[(size_t)row * HID + c0] = o;
    }
  }
}

// ---------------- CSR build ----------------
__global__ __launch_bounds__(256) void hist_kernel(const int* __restrict__ dst,
                                                   int* __restrict__ counts) {
  const int i = blockIdx.x * 256 + threadIdx.x;
  if (i < EE) atomicAdd(&counts[dst[i]], 1);
}

__global__ __launch_bounds__(256) void scan_block_sums(const int* __restrict__ counts,
                                                       int* __restrict__ bsums) {
  __shared__ int red[256];
  const int i = blockIdx.x * 256 + threadIdx.x;
  red[threadIdx.x] = (i < NN) ? counts[i] : 0;
  __syncthreads();
  for (int s = 128; s > 0; s >>= 1) {
    if (threadIdx.x < s) red[threadIdx.x] += red[threadIdx.x + s];
    __syncthreads();
  }
  if (threadIdx.x == 0) bsums[blockIdx.x] = red[0];
}

__global__ __launch_bounds__(256) void scan_bsums(int* __restrict__ bsums, int nb) {
  __shared__ int buf[2][256];
  const int t = threadIdx.x;
  const int v = (t < nb) ? bsums[t] : 0;
  int p = 0;
  buf[0][t] = v;
  __syncthreads();
  for (int off = 1; off < 256; off <<= 1) {
    buf[p ^ 1][t] = buf[p][t] + ((t >= off) ? buf[p][t - off] : 0);
    p ^= 1;
    __syncthreads();
  }
  if (t < nb) bsums[t] = buf[p][t] - v;  // exclusive
}

__global__ __launch_bounds__(256) void scan_final(const int* __restrict__ counts,
                                                  const int* __restrict__ bsums,
                                                  int* __restrict__ row_ptr,
                                                  int* __restrict__ cursor) {
  __shared__ int buf[2][256];
  const int t = threadIdx.x;
  const int i = blockIdx.x * 256 + t;
  const int v = (i < NN) ? counts[i] : 0;
  int p = 0;
  buf[0][t] = v;
  __syncthreads();
  for (int off = 1; off < 256; off <<= 1) {
    buf[p ^ 1][t] = buf[p][t] + ((t >= off) ? buf[p][t - off] : 0);
    p ^= 1;
    __syncthreads();
  }
  const int excl = buf[p][t] - v + bsums[blockIdx.x];
  if (i <= NN) row_ptr[i] = excl;   // row_ptr[NN] lands on total = EE
  if (i < NN) cursor[i] = excl;
}

__global__ __launch_bounds__(256) void scatter_kernel(
    const int* __restrict__ src, const int* __restrict__ dst,
    const float* __restrict__ w, int* __restrict__ cursor,
    int* __restrict__ ssrc, float* __restrict__ sw) {
  const int i = blockIdx.x * 256 + threadIdx.x;
  if (i < EE) {
    const int d = dst[i];
    const int pos = atomicAdd(&cursor[d], 1);
    ssrc[pos] = src[i];
    sw[pos] = w[i];
  }
}

// ---------------- SpMM: agg = A_t @ h (CSR by dst, wave per node) ----------------
__global__ __launch_bounds__(256) void spmm_csr(
    const int* __restrict__ rp, const int* __restrict__ ssrc,
    const float* __restrict__ sw, const float* __restrict__ hin,
    float* __restrict__ agg) {
  const int wid = (blockIdx.x * 256 + threadIdx.x) >> 6;  // node id
  const int lane = threadIdx.x & 63;                      // feature
  const int start = rp[wid];
  const int end = rp[wid + 1];
  float acc = 0.f;
  for (int e0 = start; e0 < end; e0 += 64) {
    const int ee = e0 + lane;
    int s = 0;
    float wgt = 0.f;
    if (ee < end) { s = ssrc[ee]; wgt = sw[ee]; }
    const int cnt = min(64, end - e0);
    for (int j = 0; j < cnt; ++j) {
      const int sj = __shfl(s, j);
      const float wj = __shfl(wgt, j);
      acc += wj * hin[(size_t)sj * HID + lane];
    }
  }
  agg[(size_t)wid * HID + lane] = acc;
}

// ------- fused layer: h = relu((1-beta)*u + beta*(u@W)), u = 0.9*agg + 0.1*x0 -------
__global__ __launch_bounds__(256) void fused_layer(
    const float* __restrict__ agg, const float* __restrict__ x0,
    const float* __restrict__ W, float beta, float* __restrict__ hout) {
  __shared__ float Wl[HID * HID];   // [k][c], 16 KB
  __shared__ float uT[HID][68];     // [k][r]
  const int t = threadIdx.x;
  const int base = blockIdx.x * 64;

  // stage W (4096 floats)
  #pragma unroll
  for (int i = 0; i < 4; ++i) {
    const int f4 = i * 256 + t;
    *(float4*)&Wl[f4 * 4] = *(const float4*)&W[f4 * 4];
  }
  // stage u tile transposed, computing the blend on the fly
  #pragma unroll
  for (int i = 0; i < 4; ++i) {
    const int f4 = i * 256 + t;
    const int row = f4 >> 4;          // 16 float4 per row
    const int col = (f4 & 15) * 4;
    float4 a = make_float4(0.f, 0.f, 0.f, 0.f);
    float4 xx = make_float4(0.f, 0.f, 0.f, 0.f);
    if (base + row < NN) {
      a = *(const float4*)&agg[(size_t)(base + row) * HID + col];
      xx = *(const float4*)&x0[(size_t)(base + row) * HID + col];
    }
    uT[col + 0][row] = 0.9f * a.x + 0.1f * xx.x;
    uT[col + 1][row] = 0.9f * a.y + 0.1f * xx.y;
    uT[col + 2][row] = 0.9f * a.z + 0.1f * xx.z;
    uT[col + 3][row] = 0.9f * a.w + 0.1f * xx.w;
  }
  __syncthreads();

  const int r0 = (t >> 4) * 4;
  const int c0 = (t & 15) * 4;
  float acc[4][4] = {};
  #pragma unroll 4
  for (int k = 0; k < HID; ++k) {
    const float4 a = *(const float4*)&uT[k][r0];
    const float4 wv = *(const float4*)&Wl[k * HID + c0];
    const float av[4] = {a.x, a.y, a.z, a.w};
    const float wvv[4] = {wv.x, wv.y, wv.z, wv.w};
    #pragma unroll
    for (int i = 0; i < 4; ++i)
      #pragma unroll
      for (int j = 0; j < 4; ++j) acc[i][j] += av[i] * wvv[j];
  }

  // epilogue: (1-beta)*u + beta*acc, relu
  float uu[4][4];
  #pragma unroll
  for (int j = 0; j < 4; ++j) {
    const float4 q = *(const float4*)&uT[c0 + j][r0];
    uu[0][j] = q.x; uu[1][j] = q.y; uu[2][j] = q.z; uu[3][j] = q.w;
  }
  const float omb = 1.f - beta;
  #pragma unroll
  for (int i = 0; i < 4; ++i) {
    const int row = base + r0 + i;
    if (row < NN) {
      float4 o;
      o.x = frelu(omb * uu[i][0] + beta * acc[i][0]);
      o.y = frelu(omb * uu[i][1] + beta * acc[i][1]);
      o.z = frelu(omb * uu[i][2] + beta * acc[i][2]);
      o.w = frelu(omb * uu[i][3] + beta * acc[i][3]);
      *(float4*)&hout[(size_t)row * HID + c0] = o;
    }
  }
}

// ---------------- output: out = h @ W_out + b_out ----------------
__global__ __launch_bounds__(256) void out_gemm(
    const float* __restrict__ hin, const float* __restrict__ W,
    const float* __restrict__ b, float* __restrict__ out) {
  __shared__ float hl[64][65];      // [r][k], pad 65 -> conflict-free reads
  __shared__ float Wl[HID * OUTCH]; // 2560 floats
  __shared__ float bl[OUTCH];
  const int t = threadIdx.x;
  const int base = blockIdx.x * 64;

  #pragma unroll
  for (int i = 0; i < 4; ++i) {
    const int f4 = i * 256 + t;
    const int row = f4 >> 4;
    const int col = (f4 & 15) * 4;
    float4 v = make_float4(0.f, 0.f, 0.f, 0.f);
    if (base + row < NN) v = *(const float4*)&hin[(size_t)(base + row) * HID + col];
    hl[row][col + 0] = v.x; hl[row][col + 1] = v.y;
    hl[row][col + 2] = v.z; hl[row][col + 3] = v.w;
  }
  for (int i = t; i < HID * OUTCH; i += 256) Wl[i] = W[i];
  if (t < OUTCH) bl[t] = b[t];
  __syncthreads();

  const int r = t & 63;
  const int g = t >> 6;   // 0..3, wave-uniform -> W reads broadcast
  const int c0 = g * 10;
  float acc[10] = {};
  for (int k = 0; k < HID; ++k) {
    const float hv = hl[r][k];
    #pragma unroll
    for (int j = 0; j < 10; ++j) acc[j] += hv * Wl[k * OUTCH + c0 + j];
  }
  const int row = base + r;
  if (row < NN) {
    #pragma unroll
    for (int j = 0; j < 10; ++j) out[(size_t)row * OUTCH + c0 + j] = acc[j] + bl[c0 + j];
  }
}

extern "C" void kernel_launch(void* const* d_in, const int* in_sizes, int n_in,
                              void* d_out, int out_size, void* d_ws, size_t ws_size,
                              hipStream_t stream) {
  const float* x     = (const float*)d_in[0];
  const int* esrc    = (const int*)d_in[1];
  const int* edst    = (const int*)d_in[2];
  const float* ew    = (const float*)d_in[3];
  const float* W_in  = (const float*)d_in[4];
  const float* b_in  = (const float*)d_in[5];
  const float* W_cv  = (const float*)d_in[6];
  const float* W_out = (const float*)d_in[7];
  const float* b_out = (const float*)d_in[8];
  float* out = (float*)d_out;

  char* w = (char*)d_ws;
  float* x0     = (float*)(w + 0);          // 12,800,000 B
  float* h      = (float*)(w + 12800000);   // 12,800,000 B
  float* agg    = (float*)(w + 25600000);   // 12,800,000 B
  int* row_ptr  = (int*)(w + 38400000);     // 200,064 B
  int* cursor   = (int*)(w + 38600064);     // 200,064 B
  int* counts   = (int*)(w + 38800128);     // 200,064 B
  int* bsums    = (int*)(w + 39000192);     // 1,024 B
  int* ssrc     = (int*)(w + 39001216);     // 3,200,000 B
  float* sw     = (float*)(w + 42201216);   // 3,200,000 B
  // total: 45,401,216 B

  const int gemm_grid = (NN + 63) / 64;        // 782
  const int edge_grid = (EE + 255) / 256;      // 3125
  const int scan_grid = (NN + 255) / 256;      // 196

  // entry linear + relu
  entry_gemm<<<gemm_grid, 256, 0, stream>>>(x, W_in, b_in, x0);

  // CSR (by dst) build — once per call
  hipMemsetAsync(counts, 0, NN * sizeof(int), stream);
  hist_kernel<<<edge_grid, 256, 0, stream>>>(edst, counts);
  scan_block_sums<<<scan_grid, 256, 0, stream>>>(counts, bsums);
  scan_bsums<<<1, 256, 0, stream>>>(bsums, scan_grid);
  scan_final<<<scan_grid, 256, 0, stream>>>(counts, bsums, row_ptr, cursor);
  scatter_kernel<<<edge_grid, 256, 0, stream>>>(esrc, edst, ew, cursor, ssrc, sw);

  // 8 GCNII layers
  const float* hin = x0;
  for (int l = 0; l < NUM_LAYERS; ++l) {
    const float beta = logf(0.5f / (float)(l + 1) + 1.0f);
    spmm_csr<<<(NN * 64) / 256, 256, 0, stream>>>(row_ptr, ssrc, sw, hin, agg);
    fused_layer<<<gemm_grid, 256, 0, stream>>>(agg, x0, W_cv + (size_t)l * HID * HID,
                                               beta, h);
    hin = h;
  }

  // output linear
  out_gemm<<<gemm_grid, 256, 0, stream>>>(h, W_out, b_out, out);
}

// Round 2
// 497.489 us; speedup vs baseline: 1.3621x; 1.3621x over previous
//
#include <hip/hip_runtime.h>
#include <math.h>

#define NN 50000
#define EE 800000
#define INCH 128
#define HID 64
#define OUTCH 40
#define NUM_LAYERS 8

__device__ __forceinline__ float frelu(float v) { return v > 0.f ? v : 0.f; }

// ---------------- entry: x0 = relu(x @ W_in + b_in) ----------------
__global__ __launch_bounds__(256) void entry_gemm(
    const float* __restrict__ x, const float* __restrict__ W,
    const float* __restrict__ b, float* __restrict__ x0) {
  __shared__ float Wl[INCH * HID];   // [k][c], 32 KB
  __shared__ float xT[INCH][68];     // [k][r], padded for alignment
  __shared__ float bl[HID];
  const int t = threadIdx.x;
  const int base = blockIdx.x * 64;

  // stage W (8192 floats) via float4
  #pragma unroll
  for (int i = 0; i < 8; ++i) {
    const int f4 = i * 256 + t;
    *(float4*)&Wl[f4 * 4] = *(const float4*)&W[f4 * 4];
  }
  if (t < HID) bl[t] = b[t];
  // stage x tile transposed (64 rows x 128 k)
  #pragma unroll
  for (int i = 0; i < 8; ++i) {
    const int f4 = i * 256 + t;
    const int row = f4 >> 5;          // 32 float4 per row
    const int col = (f4 & 31) * 4;
    float4 v = make_float4(0.f, 0.f, 0.f, 0.f);
    if (base + row < NN) v = *(const float4*)&x[(size_t)(base + row) * INCH + col];
    xT[col + 0][row] = v.x; xT[col + 1][row] = v.y;
    xT[col + 2][row] = v.z; xT[col + 3][row] = v.w;
  }
  __syncthreads();

  const int r0 = (t >> 4) * 4;
  const int c0 = (t & 15) * 4;
  float acc[4][4] = {};
  #pragma unroll 4
  for (int k = 0; k < INCH; ++k) {
    const float4 a = *(const float4*)&xT[k][r0];
    const float4 wv = *(const float4*)&Wl[k * HID + c0];
    const float av[4] = {a.x, a.y, a.z, a.w};
    const float wvv[4] = {wv.x, wv.y, wv.z, wv.w};
    #pragma unroll
    for (int i = 0; i < 4; ++i)
      #pragma unroll
      for (int j = 0; j < 4; ++j) acc[i][j] += av[i] * wvv[j];
  }

  #pragma unroll
  for (int i = 0; i < 4; ++i) {
    const int row = base + r0 + i;
    if (row < NN) {
      float4 o;
      o.x = frelu(acc[i][0] + bl[c0 + 0]);
      o.y = frelu(acc[i][1] + bl[c0 + 1]);
      o.z = frelu(acc[i][2] + bl[c0 + 2]);
      o.w = frelu(acc[i][3] + bl[c0 + 3]);
      *(float4*)&x0[(size_t)row * HID + c0] = o;
    }
  }
}

// ---------------- CSR build ----------------
__global__ __launch_bounds__(256) void hist_kernel(const int* __restrict__ dst,
                                                   int* __restrict__ counts) {
  const int i = blockIdx.x * 256 + threadIdx.x;
  if (i < EE) atomicAdd(&counts[dst[i]], 1);
}

__global__ __launch_bounds__(256) void scan_block_sums(const int* __restrict__ counts,
                                                       int* __restrict__ bsums) {
  __shared__ int red[256];
  const int i = blockIdx.x * 256 + threadIdx.x;
  red[threadIdx.x] = (i < NN) ? counts[i] : 0;
  __syncthreads();
  for (int s = 128; s > 0; s >>= 1) {
    if (threadIdx.x < s) red[threadIdx.x] += red[threadIdx.x + s];
    __syncthreads();
  }
  if (threadIdx.x == 0) bsums[blockIdx.x] = red[0];
}

__global__ __launch_bounds__(256) void scan_bsums(int* __restrict__ bsums, int nb) {
  __shared__ int buf[2][256];
  const int t = threadIdx.x;
  const int v = (t < nb) ? bsums[t] : 0;
  int p = 0;
  buf[0][t] = v;
  __syncthreads();
  for (int off = 1; off < 256; off <<= 1) {
    buf[p ^ 1][t] = buf[p][t] + ((t >= off) ? buf[p][t - off] : 0);
    p ^= 1;
    __syncthreads();
  }
  if (t < nb) bsums[t] = buf[p][t] - v;  // exclusive
}

__global__ __launch_bounds__(256) void scan_final(const int* __restrict__ counts,
                                                  const int* __restrict__ bsums,
                                                  int* __restrict__ row_ptr,
                                                  int* __restrict__ cursor) {
  __shared__ int buf[2][256];
  const int t = threadIdx.x;
  const int i = blockIdx.x * 256 + t;
  const int v = (i < NN) ? counts[i] : 0;
  int p = 0;
  buf[0][t] = v;
  __syncthreads();
  for (int off = 1; off < 256; off <<= 1) {
    buf[p ^ 1][t] = buf[p][t] + ((t >= off) ? buf[p][t - off] : 0);
    p ^= 1;
    __syncthreads();
  }
  const int excl = buf[p][t] - v + bsums[blockIdx.x];
  if (i <= NN) row_ptr[i] = excl;   // row_ptr[NN] lands on total = EE
  if (i < NN) cursor[i] = excl;
}

// scatter (src, w) interleaved as int2 -> ONE random 8B store per edge
__global__ __launch_bounds__(256) void scatter_kernel(
    const int* __restrict__ src, const int* __restrict__ dst,
    const float* __restrict__ w, int* __restrict__ cursor,
    int2* __restrict__ edges) {
  const int i = blockIdx.x * 256 + threadIdx.x;
  if (i < EE) {
    const int d = dst[i];
    const int pos = atomicAdd(&cursor[d], 1);
    edges[pos] = make_int2(src[i], __float_as_int(w[i]));
  }
}

// ---------------- SpMM: agg = A_t @ h (CSR by dst, wave per node) ----------------
// lane = feature; gathers unrolled x4 so 4 h-row loads are in flight at once.
__global__ __launch_bounds__(256) void spmm_csr(
    const int* __restrict__ rp, const int2* __restrict__ edges,
    const float* __restrict__ hin, float* __restrict__ agg) {
  const int wid = (blockIdx.x * 256 + threadIdx.x) >> 6;  // node id
  const int lane = threadIdx.x & 63;                      // feature
  const int start = rp[wid];
  const int end = rp[wid + 1];
  float acc = 0.f;
  for (int e0 = start; e0 < end; e0 += 64) {
    const int ee = e0 + lane;
    int2 ed = make_int2(0, 0);
    if (ee < end) ed = edges[ee];
    const int s = ed.x;
    const float wgt = __int_as_float(ed.y);
    const int cnt = min(64, end - e0);
    int j = 0;
    for (; j + 3 < cnt; j += 4) {
      const int s0 = __shfl(s, j + 0);
      const int s1 = __shfl(s, j + 1);
      const int s2 = __shfl(s, j + 2);
      const int s3 = __shfl(s, j + 3);
      const float w0 = __shfl(wgt, j + 0);
      const float w1 = __shfl(wgt, j + 1);
      const float w2 = __shfl(wgt, j + 2);
      const float w3 = __shfl(wgt, j + 3);
      const float f0 = hin[(size_t)s0 * HID + lane];
      const float f1 = hin[(size_t)s1 * HID + lane];
      const float f2 = hin[(size_t)s2 * HID + lane];
      const float f3 = hin[(size_t)s3 * HID + lane];
      acc += w0 * f0;
      acc += w1 * f1;
      acc += w2 * f2;
      acc += w3 * f3;
    }
    for (; j < cnt; ++j) {
      const int sj = __shfl(s, j);
      const float wj = __shfl(wgt, j);
      acc += wj * hin[(size_t)sj * HID + lane];
    }
  }
  agg[(size_t)wid * HID + lane] = acc;
}

// ------- fused layer: h = relu((1-beta)*u + beta*(u@W)), u = 0.9*agg + 0.1*x0 -------
__global__ __launch_bounds__(256) void fused_layer(
    const float* __restrict__ agg, const float* __restrict__ x0,
    const float* __restrict__ W, float beta, float* __restrict__ hout) {
  __shared__ float Wl[HID * HID];   // [k][c], 16 KB
  __shared__ float uT[HID][68];     // [k][r]
  const int t = threadIdx.x;
  const int base = blockIdx.x * 64;

  // stage W (4096 floats)
  #pragma unroll
  for (int i = 0; i < 4; ++i) {
    const int f4 = i * 256 + t;
    *(float4*)&Wl[f4 * 4] = *(const float4*)&W[f4 * 4];
  }
  // stage u tile transposed, computing the blend on the fly
  #pragma unroll
  for (int i = 0; i < 4; ++i) {
    const int f4 = i * 256 + t;
    const int row = f4 >> 4;          // 16 float4 per row
    const int col = (f4 & 15) * 4;
    float4 a = make_float4(0.f, 0.f, 0.f, 0.f);
    float4 xx = make_float4(0.f, 0.f, 0.f, 0.f);
    if (base + row < NN) {
      a = *(const float4*)&agg[(size_t)(base + row) * HID + col];
      xx = *(const float4*)&x0[(size_t)(base + row) * HID + col];
    }
    uT[col + 0][row] = 0.9f * a.x + 0.1f * xx.x;
    uT[col + 1][row] = 0.9f * a.y + 0.1f * xx.y;
    uT[col + 2][row] = 0.9f * a.z + 0.1f * xx.z;
    uT[col + 3][row] = 0.9f * a.w + 0.1f * xx.w;
  }
  __syncthreads();

  const int r0 = (t >> 4) * 4;
  const int c0 = (t & 15) * 4;
  float acc[4][4] = {};
  #pragma unroll 4
  for (int k = 0; k < HID; ++k) {
    const float4 a = *(const float4*)&uT[k][r0];
    const float4 wv = *(const float4*)&Wl[k * HID + c0];
    const float av[4] = {a.x, a.y, a.z, a.w};
    const float wvv[4] = {wv.x, wv.y, wv.z, wv.w};
    #pragma unroll
    for (int i = 0; i < 4; ++i)
      #pragma unroll
      for (int j = 0; j < 4; ++j) acc[i][j] += av[i] * wvv[j];
  }

  // epilogue: (1-beta)*u + beta*acc, relu
  float uu[4][4];
  #pragma unroll
  for (int j = 0; j < 4; ++j) {
    const float4 q = *(const float4*)&uT[c0 + j][r0];
    uu[0][j] = q.x; uu[1][j] = q.y; uu[2][j] = q.z; uu[3][j] = q.w;
  }
  const float omb = 1.f - beta;
  #pragma unroll
  for (int i = 0; i < 4; ++i) {
    const int row = base + r0 + i;
    if (row < NN) {
      float4 o;
      o.x = frelu(omb * uu[i][0] + beta * acc[i][0]);
      o.y = frelu(omb * uu[i][1] + beta * acc[i][1]);
      o.z = frelu(omb * uu[i][2] + beta * acc[i][2]);
      o.w = frelu(omb * uu[i][3] + beta * acc[i][3]);
      *(float4*)&hout[(size_t)row * HID + c0] = o;
    }
  }
}

// ---------------- output: out = h @ W_out + b_out ----------------
__global__ __launch_bounds__(256) void out_gemm(
    const float* __restrict__ hin, const float* __restrict__ W,
    const float* __restrict__ b, float* __restrict__ out) {
  __shared__ float hl[64][65];      // [r][k], pad 65 -> conflict-free reads
  __shared__ float Wl[HID * OUTCH]; // 2560 floats
  __shared__ float bl[OUTCH];
  const int t = threadIdx.x;
  const int base = blockIdx.x * 64;

  #pragma unroll
  for (int i = 0; i < 4; ++i) {
    const int f4 = i * 256 + t;
    const int row = f4 >> 4;
    const int col = (f4 & 15) * 4;
    float4 v = make_float4(0.f, 0.f, 0.f, 0.f);
    if (base + row < NN) v = *(const float4*)&hin[(size_t)(base + row) * HID + col];
    hl[row][col + 0] = v.x; hl[row][col + 1] = v.y;
    hl[row][col + 2] = v.z; hl[row][col + 3] = v.w;
  }
  for (int i = t; i < HID * OUTCH; i += 256) Wl[i] = W[i];
  if (t < OUTCH) bl[t] = b[t];
  __syncthreads();

  const int r = t & 63;
  const int g = t >> 6;   // 0..3, wave-uniform -> W reads broadcast
  const int c0 = g * 10;
  float acc[10] = {};
  for (int k = 0; k < HID; ++k) {
    const float hv = hl[r][k];
    #pragma unroll
    for (int j = 0; j < 10; ++j) acc[j] += hv * Wl[k * OUTCH + c0 + j];
  }
  const int row = base + r;
  if (row < NN) {
    #pragma unroll
    for (int j = 0; j < 10; ++j) out[(size_t)row * OUTCH + c0 + j] = acc[j] + bl[c0 + j];
  }
}

extern "C" void kernel_launch(void* const* d_in, const int* in_sizes, int n_in,
                              void* d_out, int out_size, void* d_ws, size_t ws_size,
                              hipStream_t stream) {
  const float* x     = (const float*)d_in[0];
  const int* esrc    = (const int*)d_in[1];
  const int* edst    = (const int*)d_in[2];
  const float* ew    = (const float*)d_in[3];
  const float* W_in  = (const float*)d_in[4];
  const float* b_in  = (const float*)d_in[5];
  const float* W_cv  = (const float*)d_in[6];
  const float* W_out = (const float*)d_in[7];
  const float* b_out = (const float*)d_in[8];
  float* out = (float*)d_out;

  char* w = (char*)d_ws;
  float* x0     = (float*)(w + 0);          // 12,800,000 B
  float* h      = (float*)(w + 12800000);   // 12,800,000 B
  float* agg    = (float*)(w + 25600000);   // 12,800,000 B
  int* row_ptr  = (int*)(w + 38400000);     // 200,064 B
  int* cursor   = (int*)(w + 38600064);     // 200,064 B
  int* counts   = (int*)(w + 38800128);     // 200,064 B
  int* bsums    = (int*)(w + 39000192);     // 1,024 B
  int2* edges   = (int2*)(w + 39001216);    // 6,400,000 B (src,w interleaved)
  // total: 45,401,216 B

  const int gemm_grid = (NN + 63) / 64;        // 782
  const int edge_grid = (EE + 255) / 256;      // 3125
  const int scan_grid = (NN + 255) / 256;      // 196

  // entry linear + relu
  entry_gemm<<<gemm_grid, 256, 0, stream>>>(x, W_in, b_in, x0);

  // CSR (by dst) build — once per call
  hipMemsetAsync(counts, 0, NN * sizeof(int), stream);
  hist_kernel<<<edge_grid, 256, 0, stream>>>(edst, counts);
  scan_block_sums<<<scan_grid, 256, 0, stream>>>(counts, bsums);
  scan_bsums<<<1, 256, 0, stream>>>(bsums, scan_grid);
  scan_final<<<scan_grid, 256, 0, stream>>>(counts, bsums, row_ptr, cursor);
  scatter_kernel<<<edge_grid, 256, 0, stream>>>(esrc, edst, ew, cursor, edges);

  // 8 GCNII layers
  const float* hin = x0;
  for (int l = 0; l < NUM_LAYERS; ++l) {
    const float beta = logf(0.5f / (float)(l + 1) + 1.0f);
    spmm_csr<<<(NN * 64) / 256, 256, 0, stream>>>(row_ptr, edges, hin, agg);
    fused_layer<<<gemm_grid, 256, 0, stream>>>(agg, x0, W_cv + (size_t)l * HID * HID,
                                               beta, h);
    hin = h;
  }

  // output linear
  out_gemm<<<gemm_grid, 256, 0, stream>>>(h, W_out, b_out, out);
}

// Round 3
// 436.725 us; speedup vs baseline: 1.5516x; 1.1391x over previous
//
#include <hip/hip_runtime.h>
#include <math.h>

#define NN 50000
#define EE 800000
#define INCH 128
#define HID 64
#define OUTCH 40
#define NUM_LAYERS 8

__device__ __forceinline__ float frelu(float v) { return v > 0.f ? v : 0.f; }

// round-to-nearest-even float -> bf16 (as u16)
__device__ __forceinline__ unsigned int f2bf(float f) {
  unsigned int u = __float_as_uint(f);
  return (u + 0x7fffu + ((u >> 16) & 1u)) >> 16;
}
__device__ __forceinline__ float bf_lo(unsigned int v) { return __uint_as_float(v << 16); }
__device__ __forceinline__ float bf_hi(unsigned int v) { return __uint_as_float(v & 0xffff0000u); }

// ---------------- entry: x0 = relu(x @ W_in + b_in) ----------------
// writes x0 fp32 (for residual blend) AND packed bf16 (for spmm gather)
__global__ __launch_bounds__(256) void entry_gemm(
    const float* __restrict__ x, const float* __restrict__ W,
    const float* __restrict__ b, float* __restrict__ x0,
    unsigned int* __restrict__ x0h) {
  __shared__ float Wl[INCH * HID];   // [k][c], 32 KB
  __shared__ float xT[INCH][68];     // [k][r]
  __shared__ float bl[HID];
  const int t = threadIdx.x;
  const int base = blockIdx.x * 64;

  #pragma unroll
  for (int i = 0; i < 8; ++i) {
    const int f4 = i * 256 + t;
    *(float4*)&Wl[f4 * 4] = *(const float4*)&W[f4 * 4];
  }
  if (t < HID) bl[t] = b[t];
  #pragma unroll
  for (int i = 0; i < 8; ++i) {
    const int f4 = i * 256 + t;
    const int row = f4 >> 5;
    const int col = (f4 & 31) * 4;
    float4 v = make_float4(0.f, 0.f, 0.f, 0.f);
    if (base + row < NN) v = *(const float4*)&x[(size_t)(base + row) * INCH + col];
    xT[col + 0][row] = v.x; xT[col + 1][row] = v.y;
    xT[col + 2][row] = v.z; xT[col + 3][row] = v.w;
  }
  __syncthreads();

  const int r0 = (t >> 4) * 4;
  const int c0 = (t & 15) * 4;
  float acc[4][4] = {};
  #pragma unroll 4
  for (int k = 0; k < INCH; ++k) {
    const float4 a = *(const float4*)&xT[k][r0];
    const float4 wv = *(const float4*)&Wl[k * HID + c0];
    const float av[4] = {a.x, a.y, a.z, a.w};
    const float wvv[4] = {wv.x, wv.y, wv.z, wv.w};
    #pragma unroll
    for (int i = 0; i < 4; ++i)
      #pragma unroll
      for (int j = 0; j < 4; ++j) acc[i][j] += av[i] * wvv[j];
  }

  #pragma unroll
  for (int i = 0; i < 4; ++i) {
    const int row = base + r0 + i;
    if (row < NN) {
      float4 o;
      o.x = frelu(acc[i][0] + bl[c0 + 0]);
      o.y = frelu(acc[i][1] + bl[c0 + 1]);
      o.z = frelu(acc[i][2] + bl[c0 + 2]);
      o.w = frelu(acc[i][3] + bl[c0 + 3]);
      *(float4*)&x0[(size_t)row * HID + c0] = o;
      uint2 pw;
      pw.x = f2bf(o.x) | (f2bf(o.y) << 16);
      pw.y = f2bf(o.z) | (f2bf(o.w) << 16);
      *(uint2*)&x0h[(size_t)row * 32 + (c0 >> 1)] = pw;
    }
  }
}

// ---------------- CSR build ----------------
__global__ __launch_bounds__(256) void hist_kernel(const int* __restrict__ dst,
                                                   int* __restrict__ counts) {
  const int i = blockIdx.x * 256 + threadIdx.x;
  if (i < EE) atomicAdd(&counts[dst[i]], 1);
}

__global__ __launch_bounds__(256) void scan_block_sums(const int* __restrict__ counts,
                                                       int* __restrict__ bsums) {
  __shared__ int red[256];
  const int i = blockIdx.x * 256 + threadIdx.x;
  red[threadIdx.x] = (i < NN) ? counts[i] : 0;
  __syncthreads();
  for (int s = 128; s > 0; s >>= 1) {
    if (threadIdx.x < s) red[threadIdx.x] += red[threadIdx.x + s];
    __syncthreads();
  }
  if (threadIdx.x == 0) bsums[blockIdx.x] = red[0];
}

__global__ __launch_bounds__(256) void scan_bsums(int* __restrict__ bsums, int nb) {
  __shared__ int buf[2][256];
  const int t = threadIdx.x;
  const int v = (t < nb) ? bsums[t] : 0;
  int p = 0;
  buf[0][t] = v;
  __syncthreads();
  for (int off = 1; off < 256; off <<= 1) {
    buf[p ^ 1][t] = buf[p][t] + ((t >= off) ? buf[p][t - off] : 0);
    p ^= 1;
    __syncthreads();
  }
  if (t < nb) bsums[t] = buf[p][t] - v;  // exclusive
}

__global__ __launch_bounds__(256) void scan_final(const int* __restrict__ counts,
                                                  const int* __restrict__ bsums,
                                                  int* __restrict__ row_ptr,
                                                  int* __restrict__ cursor) {
  __shared__ int buf[2][256];
  const int t = threadIdx.x;
  const int i = blockIdx.x * 256 + t;
  const int v = (i < NN) ? counts[i] : 0;
  int p = 0;
  buf[0][t] = v;
  __syncthreads();
  for (int off = 1; off < 256; off <<= 1) {
    buf[p ^ 1][t] = buf[p][t] + ((t >= off) ? buf[p][t - off] : 0);
    p ^= 1;
    __syncthreads();
  }
  const int excl = buf[p][t] - v + bsums[blockIdx.x];
  if (i <= NN) row_ptr[i] = excl;
  if (i < NN) cursor[i] = excl;
}

// scatter (src, w) interleaved as int2 -> ONE random 8B store per edge
__global__ __launch_bounds__(256) void scatter_kernel(
    const int* __restrict__ src, const int* __restrict__ dst,
    const float* __restrict__ w, int* __restrict__ cursor,
    int2* __restrict__ edges) {
  const int i = blockIdx.x * 256 + threadIdx.x;
  if (i < EE) {
    const int d = dst[i];
    const int pos = atomicAdd(&cursor[d], 1);
    edges[pos] = make_int2(src[i], __float_as_int(w[i]));
  }
}

// ---------------- SpMM: agg = A_t @ h (CSR by dst, wave per node) ----------------
// h packed bf16: row = 32 uint32 (128 B). Half-wave per edge: lanes 0-31 edge j,
// lanes 32-63 edge j+1. Unrolled so 4 gathers (8 edges) are in flight.
__global__ __launch_bounds__(256) void spmm_csr(
    const int* __restrict__ rp, const int2* __restrict__ edges,
    const unsigned int* __restrict__ hin, float* __restrict__ agg) {
  const int wid = (blockIdx.x * 256 + threadIdx.x) >> 6;  // node id
  const int lane = threadIdx.x & 63;
  const int cp = lane & 31;        // feature-pair index
  const int half = lane >> 5;      // which edge of the pair
  const int start = rp[wid];
  const int end = rp[wid + 1];
  float ax = 0.f, ay = 0.f;
  for (int e0 = start; e0 < end; e0 += 64) {
    const int ee = e0 + lane;
    int2 ed = make_int2(0, 0);
    if (ee < end) ed = edges[ee];              // lanes >= cnt keep w = 0
    const int s = ed.x;
    const float wgt = __int_as_float(ed.y);
    const int cnt = min(64, end - e0);
    int j = 0;
    for (; j + 7 < cnt; j += 8) {
      const int j0 = j + half, j1 = j + 2 + half, j2 = j + 4 + half, j3 = j + 6 + half;
      const int s0 = __shfl(s, j0);
      const int s1 = __shfl(s, j1);
      const int s2 = __shfl(s, j2);
      const int s3 = __shfl(s, j3);
      const float w0 = __shfl(wgt, j0);
      const float w1 = __shfl(wgt, j1);
      const float w2 = __shfl(wgt, j2);
      const float w3 = __shfl(wgt, j3);
      const unsigned int h0 = hin[(size_t)s0 * 32 + cp];
      const unsigned int h1 = hin[(size_t)s1 * 32 + cp];
      const unsigned int h2 = hin[(size_t)s2 * 32 + cp];
      const unsigned int h3 = hin[(size_t)s3 * 32 + cp];
      ax += w0 * bf_lo(h0); ay += w0 * bf_hi(h0);
      ax += w1 * bf_lo(h1); ay += w1 * bf_hi(h1);
      ax += w2 * bf_lo(h2); ay += w2 * bf_hi(h2);
      ax += w3 * bf_lo(h3); ay += w3 * bf_hi(h3);
    }
    for (; j < cnt; j += 2) {
      const int jj = j + half;                 // jj==cnt lands on a w=0 lane
      const int sj = __shfl(s, jj);
      const float wj = __shfl(wgt, jj);
      const unsigned int hv = hin[(size_t)sj * 32 + cp];
      ax += wj * bf_lo(hv);
      ay += wj * bf_hi(hv);
    }
  }
  // combine the two half-wave partial sums
  ax += __shfl_xor(ax, 32);
  ay += __shfl_xor(ay, 32);
  if (half == 0) {
    *(float2*)&agg[(size_t)wid * HID + 2 * cp] = make_float2(ax, ay);
  }
}

// ------- fused layer: h = relu((1-beta)*u + beta*(u@W)), u = 0.9*agg + 0.1*x0 -------
// output packed bf16
__global__ __launch_bounds__(256) void fused_layer(
    const float* __restrict__ agg, const float* __restrict__ x0,
    const float* __restrict__ W, float beta, unsigned int* __restrict__ hout) {
  __shared__ float Wl[HID * HID];   // [k][c], 16 KB
  __shared__ float uT[HID][68];     // [k][r]
  const int t = threadIdx.x;
  const int base = blockIdx.x * 64;

  #pragma unroll
  for (int i = 0; i < 4; ++i) {
    const int f4 = i * 256 + t;
    *(float4*)&Wl[f4 * 4] = *(const float4*)&W[f4 * 4];
  }
  #pragma unroll
  for (int i = 0; i < 4; ++i) {
    const int f4 = i * 256 + t;
    const int row = f4 >> 4;
    const int col = (f4 & 15) * 4;
    float4 a = make_float4(0.f, 0.f, 0.f, 0.f);
    float4 xx = make_float4(0.f, 0.f, 0.f, 0.f);
    if (base + row < NN) {
      a = *(const float4*)&agg[(size_t)(base + row) * HID + col];
      xx = *(const float4*)&x0[(size_t)(base + row) * HID + col];
    }
    uT[col + 0][row] = 0.9f * a.x + 0.1f * xx.x;
    uT[col + 1][row] = 0.9f * a.y + 0.1f * xx.y;
    uT[col + 2][row] = 0.9f * a.z + 0.1f * xx.z;
    uT[col + 3][row] = 0.9f * a.w + 0.1f * xx.w;
  }
  __syncthreads();

  const int r0 = (t >> 4) * 4;
  const int c0 = (t & 15) * 4;
  float acc[4][4] = {};
  #pragma unroll 4
  for (int k = 0; k < HID; ++k) {
    const float4 a = *(const float4*)&uT[k][r0];
    const float4 wv = *(const float4*)&Wl[k * HID + c0];
    const float av[4] = {a.x, a.y, a.z, a.w};
    const float wvv[4] = {wv.x, wv.y, wv.z, wv.w};
    #pragma unroll
    for (int i = 0; i < 4; ++i)
      #pragma unroll
      for (int j = 0; j < 4; ++j) acc[i][j] += av[i] * wvv[j];
  }

  float uu[4][4];
  #pragma unroll
  for (int j = 0; j < 4; ++j) {
    const float4 q = *(const float4*)&uT[c0 + j][r0];
    uu[0][j] = q.x; uu[1][j] = q.y; uu[2][j] = q.z; uu[3][j] = q.w;
  }
  const float omb = 1.f - beta;
  #pragma unroll
  for (int i = 0; i < 4; ++i) {
    const int row = base + r0 + i;
    if (row < NN) {
      const float o0 = frelu(omb * uu[i][0] + beta * acc[i][0]);
      const float o1 = frelu(omb * uu[i][1] + beta * acc[i][1]);
      const float o2 = frelu(omb * uu[i][2] + beta * acc[i][2]);
      const float o3 = frelu(omb * uu[i][3] + beta * acc[i][3]);
      uint2 pw;
      pw.x = f2bf(o0) | (f2bf(o1) << 16);
      pw.y = f2bf(o2) | (f2bf(o3) << 16);
      *(uint2*)&hout[(size_t)row * 32 + (c0 >> 1)] = pw;
    }
  }
}

// ---------------- output: out = h @ W_out + b_out (h packed bf16) ----------------
__global__ __launch_bounds__(256) void out_gemm(
    const unsigned int* __restrict__ hp, const float* __restrict__ W,
    const float* __restrict__ b, float* __restrict__ out) {
  __shared__ float hl[64][65];
  __shared__ float Wl[HID * OUTCH];
  __shared__ float bl[OUTCH];
  const int t = threadIdx.x;
  const int base = blockIdx.x * 64;

  #pragma unroll
  for (int i = 0; i < 8; ++i) {
    const int idx = i * 256 + t;      // 2048 packed words per tile
    const int row = idx >> 5;
    const int c = idx & 31;
    unsigned int v = 0;
    if (base + row < NN) v = hp[(size_t)(base + row) * 32 + c];
    hl[row][2 * c + 0] = bf_lo(v);
    hl[row][2 * c + 1] = bf_hi(v);
  }
  for (int i = t; i < HID * OUTCH; i += 256) Wl[i] = W[i];
  if (t < OUTCH) bl[t] = b[t];
  __syncthreads();

  const int r = t & 63;
  const int g = t >> 6;
  const int c0 = g * 10;
  float acc[10] = {};
  for (int k = 0; k < HID; ++k) {
    const float hv = hl[r][k];
    #pragma unroll
    for (int j = 0; j < 10; ++j) acc[j] += hv * Wl[k * OUTCH + c0 + j];
  }
  const int row = base + r;
  if (row < NN) {
    #pragma unroll
    for (int j = 0; j < 10; ++j) out[(size_t)row * OUTCH + c0 + j] = acc[j] + bl[c0 + j];
  }
}

extern "C" void kernel_launch(void* const* d_in, const int* in_sizes, int n_in,
                              void* d_out, int out_size, void* d_ws, size_t ws_size,
                              hipStream_t stream) {
  const float* x     = (const float*)d_in[0];
  const int* esrc    = (const int*)d_in[1];
  const int* edst    = (const int*)d_in[2];
  const float* ew    = (const float*)d_in[3];
  const float* W_in  = (const float*)d_in[4];
  const float* b_in  = (const float*)d_in[5];
  const float* W_cv  = (const float*)d_in[6];
  const float* W_out = (const float*)d_in[7];
  const float* b_out = (const float*)d_in[8];
  float* out = (float*)d_out;

  char* w = (char*)d_ws;
  float* x0          = (float*)(w + 0);          // 12,800,000 B  fp32 x0
  unsigned int* x0h  = (unsigned int*)(w + 12800000); // 6,400,000 B  bf16 x0
  unsigned int* hb   = (unsigned int*)(w + 19200000); // 6,400,000 B  bf16 h
  float* agg         = (float*)(w + 25600000);   // 12,800,000 B
  int* row_ptr       = (int*)(w + 38400000);     // 200,064 B
  int* cursor        = (int*)(w + 38600064);     // 200,064 B
  int* counts        = (int*)(w + 38800128);     // 200,064 B
  int* bsums         = (int*)(w + 39000192);     // 1,024 B
  int2* edges        = (int2*)(w + 39001216);    // 6,400,000 B
  // total: 45,401,216 B

  const int gemm_grid = (NN + 63) / 64;        // 782
  const int edge_grid = (EE + 255) / 256;      // 3125
  const int scan_grid = (NN + 255) / 256;      // 196

  entry_gemm<<<gemm_grid, 256, 0, stream>>>(x, W_in, b_in, x0, x0h);

  hipMemsetAsync(counts, 0, NN * sizeof(int), stream);
  hist_kernel<<<edge_grid, 256, 0, stream>>>(edst, counts);
  scan_block_sums<<<scan_grid, 256, 0, stream>>>(counts, bsums);
  scan_bsums<<<1, 256, 0, stream>>>(bsums, scan_grid);
  scan_final<<<scan_grid, 256, 0, stream>>>(counts, bsums, row_ptr, cursor);
  scatter_kernel<<<edge_grid, 256, 0, stream>>>(esrc, edst, ew, cursor, edges);

  const unsigned int* hin = x0h;
  for (int l = 0; l < NUM_LAYERS; ++l) {
    const float beta = logf(0.5f / (float)(l + 1) + 1.0f);
    spmm_csr<<<(NN * 64) / 256, 256, 0, stream>>>(row_ptr, edges, hin, agg);
    fused_layer<<<gemm_grid, 256, 0, stream>>>(agg, x0, W_cv + (size_t)l * HID * HID,
                                               beta, hb);
    hin = hb;
  }

  out_gemm<<<gemm_grid, 256, 0, stream>>>(hb, W_out, b_out, out);
}